// Round 1
// baseline (621.024 us; speedup 1.0000x reference)
//
#include <hip/hip_runtime.h>
#include <math.h>

#define BB 8
#define NPTS 80000
#define KK 5
#define FF 20
#define GG 192                 // blocks per batch -> 1536 blocks = 6 blocks/CU exactly
#define TILE 128
#define NTILES (NPTS / TILE)   // 625, exact
#define PSTRIDE 48             // padded partial row: 20 s1 + 20 s2 + 1 s0 + pad

// workspace layout (float offsets) -- small params/coefs only
#define WS_CM 0          // cur means  [B,K,F] = 800
#define WS_CV 800        // cur var    = 800
#define WS_CP 1600       // cur pi     = 40
#define WS_A  1640       // A coef     = 40
#define WS_D  1680       // d coef     = 800
#define WS_E  2480       // e coef     = 800

// ---- compute A/d/e from (means,var,pi) ----
__device__ __forceinline__ void make_coefs(const float* __restrict__ means,
                                           const float* __restrict__ var,
                                           const float* __restrict__ pi,
                                           float* __restrict__ A, float* __restrict__ D,
                                           float* __restrict__ E, int t) {
    if (t < BB * KK) {
        float sumlog = 0.f, summ2 = 0.f;
        for (int f = 0; f < FF; ++f) {
            float v = var[t * FF + f];
            float m = means[t * FF + f];
            float ic = 1.f / (v + 1e-6f);
            sumlog += logf(6.283185307179586f * v);
            summ2  += ic * m * m;
            D[t * FF + f] = ic * m;
            E[t * FF + f] = -0.5f * ic;
        }
        A[t] = logf(pi[t]) - 0.5f * sumlog - 0.5f * summ2;
    }
}

__global__ void prepare_kernel(const float* __restrict__ means, const float* __restrict__ var,
                               const float* __restrict__ pi, float* __restrict__ ws) {
    make_coefs(means, var, pi, ws + WS_A, ws + WS_D, ws + WS_E, (int)threadIdx.x);
}

// ---- E-step: per-wave cluster, 2 points per lane, double-buffered LDS tile ----
// 320 threads = 5 waves (one per cluster). TILE=128 points staged per iteration
// (each thread stages 8 consecutive floats = 2 float4). xs is double-buffered so
// the accumulate phase can re-read the tile from LDS after the lls barrier without
// racing the next iteration's staging writes (buf t and t+2 are separated by two
// barriers). launch_bounds(320,8) caps VGPR at 64 -> 6 blocks/CU = 30 waves/CU.
template <bool WRITE_OUT>
__global__ __launch_bounds__(320, 8) void estep_kernel(const float* __restrict__ data,
                                                       const float* __restrict__ ws,
                                                       float* __restrict__ partials,
                                                       float* __restrict__ out_ll,
                                                       float* __restrict__ out_post) {
    __shared__ float xs[2][FF][TILE + 1];   // transposed: x[f]=xs[buf][f][p], stride-1 reads
    __shared__ float lls[KK][TILE];

    const int b    = blockIdx.x / GG;
    const int g    = blockIdx.x % GG;
    const int tid  = threadIdx.x;
    const int w    = __builtin_amdgcn_readfirstlane(tid >> 6);   // cluster k, wave-uniform
    const int lane = tid & 63;
    const int fi   = tid * 8;                 // first staged float index in tile
    const int sp0  = fi / FF,       sf0 = fi % FF;        // 4-aligned feature block
    const int sp1  = (fi + 4) / FF, sf1 = (fi + 4) % FF;

    const float* A = ws + WS_A;
    const float* D = ws + WS_D;
    const float* E = ws + WS_E;

    const float Ak = A[b * KK + w];
    float dk[FF], ek[FF];                 // wave-uniform -> SGPRs
#pragma unroll
    for (int f = 0; f < FF; ++f) {
        dk[f] = D[(b * KK + w) * FF + f];
        ek[f] = E[(b * KK + w) * FF + f];
    }

    float s0 = 0.f, s1[FF], s2[FF];
    if (!WRITE_OUT) {
#pragma unroll
        for (int f = 0; f < FF; ++f) { s1[f] = 0.f; s2[f] = 0.f; }
    }

    const float* dbase = data + (size_t)b * NPTS * FF;

    // software prefetch: tile t's 32B loaded one full iteration ahead
    const float4* tpf = (const float4*)(dbase + (size_t)g * TILE * FF);
    float4 va = tpf[2 * tid];
    float4 vb = tpf[2 * tid + 1];
    int buf = 0;

    for (int t = g; t < NTILES; t += GG) {
        const int tn = t + GG;
        float4 na = va, nb = vb;
        if (tn < NTILES) {
            const float4* tp = (const float4*)(dbase + (size_t)tn * TILE * FF);
            na = tp[2 * tid];
            nb = tp[2 * tid + 1];
        }

        xs[buf][sf0][sp0]     = va.x;
        xs[buf][sf0 + 1][sp0] = va.y;
        xs[buf][sf0 + 2][sp0] = va.z;
        xs[buf][sf0 + 3][sp0] = va.w;
        xs[buf][sf1][sp1]     = vb.x;
        xs[buf][sf1 + 1][sp1] = vb.y;
        xs[buf][sf1 + 2][sp1] = vb.z;
        xs[buf][sf1 + 3][sp1] = vb.w;
        __syncthreads();

        float z0 = Ak, z1 = Ak;
#pragma unroll
        for (int f = 0; f < FF; ++f) {
            float x0 = xs[buf][f][lane];
            float x1 = xs[buf][f][lane + 64];
            z0 += x0 * fmaf(ek[f], x0, dk[f]);
            z1 += x1 * fmaf(ek[f], x1, dk[f]);
        }
        lls[w][lane]      = z0;
        lls[w][lane + 64] = z1;
        __syncthreads();

        // softmax for point p0 = lane
        float a0 = lls[0][lane], a1 = lls[1][lane], a2 = lls[2][lane],
              a3 = lls[3][lane], a4 = lls[4][lane];
        float mx0 = fmaxf(fmaxf(fmaxf(a0, a1), fmaxf(a2, a3)), a4);
        float e0 = __expf(a0 - mx0), e1 = __expf(a1 - mx0), e2 = __expf(a2 - mx0),
              e3 = __expf(a3 - mx0), e4 = __expf(a4 - mx0);
        float inv0 = 1.f / (e0 + e1 + e2 + e3 + e4);
        float ew0  = (w == 0) ? e0 : (w == 1) ? e1 : (w == 2) ? e2 : (w == 3) ? e3 : e4;
        float post0 = ew0 * inv0;

        // softmax for point p1 = lane + 64
        float b0 = lls[0][lane + 64], b1 = lls[1][lane + 64], b2 = lls[2][lane + 64],
              b3 = lls[3][lane + 64], b4 = lls[4][lane + 64];
        float mx1 = fmaxf(fmaxf(fmaxf(b0, b1), fmaxf(b2, b3)), b4);
        float f0 = __expf(b0 - mx1), f1 = __expf(b1 - mx1), f2 = __expf(b2 - mx1),
              f3 = __expf(b3 - mx1), f4 = __expf(b4 - mx1);
        float inv1 = 1.f / (f0 + f1 + f2 + f3 + f4);
        float ew1  = (w == 0) ? f0 : (w == 1) ? f1 : (w == 2) ? f2 : (w == 3) ? f3 : f4;
        float post1 = ew1 * inv1;

        if (WRITE_OUT) {
            size_t o0 = ((size_t)b * NPTS + (size_t)t * TILE + lane) * KK + w;
            out_ll[o0]   = z0;
            out_post[o0] = post0;
            size_t o1 = o0 + (size_t)64 * KK;
            out_ll[o1]   = z1;
            out_post[o1] = post1;
        } else {
            s0 += post0 + post1;
#pragma unroll
            for (int f = 0; f < FF; ++f) {
                float x0 = xs[buf][f][lane];        // re-read LDS: race-safe (dbuf)
                float x1 = xs[buf][f][lane + 64];
                float q0 = post0 * x0;
                float q1 = post1 * x1;
                s1[f] += q0 + q1;
                s2[f] = fmaf(q0, x0, s2[f]);
                s2[f] = fmaf(q1, x1, s2[f]);
            }
        }
        va = na; vb = nb; buf ^= 1;
    }

    if (!WRITE_OUT) {
#pragma unroll
        for (int off = 32; off > 0; off >>= 1) {
            s0 += __shfl_down(s0, off);
#pragma unroll
            for (int f = 0; f < FF; ++f) {
                s1[f] += __shfl_down(s1[f], off);
                s2[f] += __shfl_down(s2[f], off);
            }
        }
        if (lane == 0) {
            // unique row per (b,k,g): plain stores, zero contention
            float* row = partials + ((size_t)(b * KK + w) * GG + g) * PSTRIDE;
#pragma unroll
            for (int f = 0; f < FF; ++f) { row[f] = s1[f]; row[FF + f] = s2[f]; }
            row[2 * FF] = s0;
        }
    }
}

// ---- reduce partials + M-step + next-iteration coefs ----
// One block per (b,k) = 40 blocks (vs 8 before): 4 waves split the g-reduction
// 4-way; 40 extra threads redundantly sum the s0 column of ALL K clusters for
// the pi normalizer (Sum_k s0_k), so no cross-block exchange is needed.
__global__ __launch_bounds__(256) void update_kernel(const float* __restrict__ partials,
                                                     float* __restrict__ ws,
                                                     float* __restrict__ om,
                                                     float* __restrict__ ov,
                                                     float* __restrict__ op,
                                                     int write_params) {
    __shared__ float shA[4][PSTRIDE];
    __shared__ float shB[8 * KK];
    const int bk   = blockIdx.x;          // b*KK + k
    const int b    = bk / KK;
    const int tid  = threadIdx.x;
    const int w4   = tid >> 6;
    const int lane = tid & 63;

    // phase A: lane l sums partial slot l over g = w4..GG step 4 (coalesced rows)
    if (lane < PSTRIDE) {
        const float* base = partials + (size_t)bk * GG * PSTRIDE + lane;
        float sv = 0.f;
        for (int gg = w4; gg < GG; gg += 4) sv += base[(size_t)gg * PSTRIDE];
        shA[w4][lane] = sv;
    }
    // phase B: total cluster size over all K clusters (for pi / A)
    if (tid < 8 * KK) {
        const int kp = tid >> 3, j = tid & 7;
        const float* cb = partials + (size_t)(b * KK + kp) * GG * PSTRIDE + 2 * FF;
        float s = 0.f;
        for (int gg = j; gg < GG; gg += 8) s += cb[(size_t)gg * PSTRIDE];
        shB[tid] = s;
    }
    __syncthreads();

    if (tid < 64) {
        float svt = 0.f;
        if (lane < PSTRIDE)
            svt = shA[0][lane] + shA[1][lane] + shA[2][lane] + shA[3][lane];

        float tb = (lane < 8 * KK) ? shB[lane] : 0.f;
#pragma unroll
        for (int off = 32; off > 0; off >>= 1) tb += __shfl_xor(tb, off);
        // tb = Sum_k s0_k on every lane

        float s0  = __shfl(svt, 2 * FF);          // this cluster's size
        float den = s0 + 1e-7f;
        float m   = svt / den;                    // meaningful on lanes 0..19 (svt = S1[f])
        float s2f = __shfl(svt, FF + (lane % FF));// S2[f] for lane f
        float var = (s2f - 2.f * m * svt + m * m * s0) / den + 1e-6f;  // lanes 0..19

        float* cm = ws + WS_CM; float* cv = ws + WS_CV; float* cp = ws + WS_CP;
        if (lane < FF) {
            cm[bk * FF + lane] = m;
            cv[bk * FF + lane] = var;
            if (write_params) { om[bk * FF + lane] = m; ov[bk * FF + lane] = var; }
        }

        float pr = (s0 / (float)NPTS) / fmaxf(tb / (float)NPTS, 1e-12f);
        if (lane == 0) {
            cp[bk] = pr;
            if (write_params) op[bk] = pr;
        }

        // coefs for next E-step, computed in-register
        float ic = 1.f / (var + 1e-6f);
        if (lane < FF) {
            (ws + WS_D)[bk * FF + lane] = ic * m;
            (ws + WS_E)[bk * FF + lane] = -0.5f * ic;
        }
        float t1 = (lane < FF) ? logf(6.283185307179586f * var) : 0.f;
        float t2 = (lane < FF) ? ic * m * m : 0.f;
#pragma unroll
        for (int off = 1; off < 64; off <<= 1) {
            t1 += __shfl_xor(t1, off);
            t2 += __shfl_xor(t2, off);
        }
        if (lane == 0)
            (ws + WS_A)[bk] = logf(pr) - 0.5f * t1 - 0.5f * t2;
    }
}

extern "C" void kernel_launch(void* const* d_in, const int* in_sizes, int n_in,
                              void* d_out, int out_size, void* d_ws, size_t ws_size,
                              hipStream_t stream) {
    const float* data     = (const float*)d_in[0];
    const float* in_means = (const float*)d_in[1];
    const float* in_var   = (const float*)d_in[2];
    const float* in_pi    = (const float*)d_in[3];
    float* ws  = (float*)d_ws;
    float* out = (float*)d_out;

    float* out_ll   = out;
    float* out_post = out + (size_t)BB * NPTS * KK;
    float* om       = out + 2 * (size_t)BB * NPTS * KK;
    float* ov       = om + BB * KK * FF;
    float* op       = ov + BB * KK * FF;

    // partial-sum buffer (1.5 MB) lives in the not-yet-needed ll output region;
    // the final E-step fully overwrites it.
    float* partials = out_ll;

    prepare_kernel<<<1, 64, 0, stream>>>(in_means, in_var, in_pi, ws);

    for (int it = 0; it < 5; ++it) {
        estep_kernel<false><<<BB * GG, 320, 0, stream>>>(data, ws, partials,
                                                         nullptr, nullptr);
        update_kernel<<<BB * KK, 256, 0, stream>>>(partials, ws, om, ov, op,
                                                   (it == 4) ? 1 : 0);
    }
    // final E-step with post-loop params: write ll/post outputs
    estep_kernel<true><<<BB * GG, 320, 0, stream>>>(data, ws, nullptr,
                                                    out_ll, out_post);
}

// Round 2
// 424.922 us; speedup vs baseline: 1.4615x; 1.4615x over previous
//
#include <hip/hip_runtime.h>
#include <math.h>

#define BB 8
#define NPTS 80000
#define KK 5
#define FF 20
#define GG 192                 // blocks per batch -> 1536 blocks = 6 blocks/CU exactly
#define TILE 128
#define NTILES (NPTS / TILE)   // 625, exact
#define PSTRIDE 48             // padded partial row: 20 s1 + 20 s2 + 1 s0 + pad

// workspace layout (float offsets) -- small params/coefs only
#define WS_CM 0          // cur means  [B,K,F] = 800
#define WS_CV 800        // cur var    = 800
#define WS_CP 1600       // cur pi     = 40
#define WS_A  1640       // A coef     = 40
#define WS_D  1680       // d coef     = 800
#define WS_E  2480       // e coef     = 800

// ---- compute A/d/e from (means,var,pi) ----
__device__ __forceinline__ void make_coefs(const float* __restrict__ means,
                                           const float* __restrict__ var,
                                           const float* __restrict__ pi,
                                           float* __restrict__ A, float* __restrict__ D,
                                           float* __restrict__ E, int t) {
    if (t < BB * KK) {
        float sumlog = 0.f, summ2 = 0.f;
        for (int f = 0; f < FF; ++f) {
            float v = var[t * FF + f];
            float m = means[t * FF + f];
            float ic = 1.f / (v + 1e-6f);
            sumlog += logf(6.283185307179586f * v);
            summ2  += ic * m * m;
            D[t * FF + f] = ic * m;
            E[t * FF + f] = -0.5f * ic;
        }
        A[t] = logf(pi[t]) - 0.5f * sumlog - 0.5f * summ2;
    }
}

__global__ void prepare_kernel(const float* __restrict__ means, const float* __restrict__ var,
                               const float* __restrict__ pi, float* __restrict__ ws) {
    make_coefs(means, var, pi, ws + WS_A, ws + WS_D, ws + WS_E, (int)threadIdx.x);
}

// ---- E-step: per-wave cluster, 2 points per lane, double-buffered LDS tile ----
// 320 threads = 5 waves (one per cluster). TILE=128 points staged per iteration
// (each thread stages 8 consecutive floats = 2 float4). xs is double-buffered so
// the accumulate phase can re-read the tile from LDS after the lls barrier without
// racing the next iteration's staging writes.
// NO min-waves clause in launch_bounds: round-1 showed (320,8) clamps VGPR to 32
// and spills the 41-float accumulator state to scratch (171 MB of WRITE_SIZE).
// Unclamped, live state is ~52-60 VGPR; <=64 allows 6 blocks/CU = 30 waves.
template <bool WRITE_OUT>
__global__ __launch_bounds__(320) void estep_kernel(const float* __restrict__ data,
                                                    const float* __restrict__ ws,
                                                    float* __restrict__ partials,
                                                    float* __restrict__ out_ll,
                                                    float* __restrict__ out_post) {
    __shared__ float xs[2][FF][TILE + 1];   // transposed: x[f]=xs[buf][f][p], stride-1 reads
    __shared__ float lls[KK][TILE];

    const int b    = blockIdx.x / GG;
    const int g    = blockIdx.x % GG;
    const int tid  = threadIdx.x;
    const int w    = __builtin_amdgcn_readfirstlane(tid >> 6);   // cluster k, wave-uniform
    const int lane = tid & 63;
    const int fi   = tid * 8;                 // first staged float index in tile
    const int sp0  = fi / FF,       sf0 = fi % FF;        // 4-aligned feature block
    const int sp1  = (fi + 4) / FF, sf1 = (fi + 4) % FF;

    const float* A = ws + WS_A;
    const float* D = ws + WS_D;
    const float* E = ws + WS_E;

    const float Ak = A[b * KK + w];
    float dk[FF], ek[FF];                 // wave-uniform -> SGPRs
#pragma unroll
    for (int f = 0; f < FF; ++f) {
        dk[f] = D[(b * KK + w) * FF + f];
        ek[f] = E[(b * KK + w) * FF + f];
    }

    float s0 = 0.f, s1[FF], s2[FF];
    if (!WRITE_OUT) {
#pragma unroll
        for (int f = 0; f < FF; ++f) { s1[f] = 0.f; s2[f] = 0.f; }
    }

    const float* dbase = data + (size_t)b * NPTS * FF;

    // software prefetch: tile t's 32B loaded one iteration ahead. va/vb are
    // written to LDS FIRST, then the next-tile loads are issued, so both pairs
    // are never simultaneously live (peak prefetch state 12 floats, not 16).
    const float4* tpf = (const float4*)(dbase + (size_t)g * TILE * FF);
    float4 va = tpf[2 * tid];
    float4 vb = tpf[2 * tid + 1];
    int buf = 0;

    for (int t = g; t < NTILES; t += GG) {
        xs[buf][sf0][sp0]     = va.x;
        xs[buf][sf0 + 1][sp0] = va.y;
        xs[buf][sf0 + 2][sp0] = va.z;
        xs[buf][sf0 + 3][sp0] = va.w;
        xs[buf][sf1][sp1]     = vb.x;
        xs[buf][sf1 + 1][sp1] = vb.y;
        xs[buf][sf1 + 2][sp1] = vb.z;
        xs[buf][sf1 + 3][sp1] = vb.w;

        const int tn = t + GG;
        if (tn < NTILES) {
            const float4* tp = (const float4*)(dbase + (size_t)tn * TILE * FF);
            va = tp[2 * tid];
            vb = tp[2 * tid + 1];
        }
        __syncthreads();

        float z0 = Ak, z1 = Ak;
#pragma unroll
        for (int f = 0; f < FF; ++f) {
            float x0 = xs[buf][f][lane];
            float x1 = xs[buf][f][lane + 64];
            z0 = fmaf(x0, fmaf(ek[f], x0, dk[f]), z0);
            z1 = fmaf(x1, fmaf(ek[f], x1, dk[f]), z1);
        }
        lls[w][lane]      = z0;
        lls[w][lane + 64] = z1;
        __syncthreads();

        // softmax for point p0 = lane
        float a0 = lls[0][lane], a1 = lls[1][lane], a2 = lls[2][lane],
              a3 = lls[3][lane], a4 = lls[4][lane];
        float mx0 = fmaxf(fmaxf(fmaxf(a0, a1), fmaxf(a2, a3)), a4);
        float e0 = __expf(a0 - mx0), e1 = __expf(a1 - mx0), e2 = __expf(a2 - mx0),
              e3 = __expf(a3 - mx0), e4 = __expf(a4 - mx0);
        float inv0 = 1.f / (e0 + e1 + e2 + e3 + e4);
        float ew0  = (w == 0) ? e0 : (w == 1) ? e1 : (w == 2) ? e2 : (w == 3) ? e3 : e4;
        float post0 = ew0 * inv0;

        // softmax for point p1 = lane + 64
        float b0 = lls[0][lane + 64], b1 = lls[1][lane + 64], b2 = lls[2][lane + 64],
              b3 = lls[3][lane + 64], b4 = lls[4][lane + 64];
        float mx1 = fmaxf(fmaxf(fmaxf(b0, b1), fmaxf(b2, b3)), b4);
        float f0 = __expf(b0 - mx1), f1 = __expf(b1 - mx1), f2 = __expf(b2 - mx1),
              f3 = __expf(b3 - mx1), f4 = __expf(b4 - mx1);
        float inv1 = 1.f / (f0 + f1 + f2 + f3 + f4);
        float ew1  = (w == 0) ? f0 : (w == 1) ? f1 : (w == 2) ? f2 : (w == 3) ? f3 : f4;
        float post1 = ew1 * inv1;

        if (WRITE_OUT) {
            size_t o0 = ((size_t)b * NPTS + (size_t)t * TILE + lane) * KK + w;
            out_ll[o0]   = z0;
            out_post[o0] = post0;
            size_t o1 = o0 + (size_t)64 * KK;
            out_ll[o1]   = z1;
            out_post[o1] = post1;
        } else {
            s0 += post0 + post1;
#pragma unroll
            for (int f = 0; f < FF; ++f) {
                float x0 = xs[buf][f][lane];        // re-read LDS: race-safe (dbuf)
                float x1 = xs[buf][f][lane + 64];
                float q0 = post0 * x0;
                float q1 = post1 * x1;
                s1[f] += q0 + q1;
                s2[f] = fmaf(q0, x0, s2[f]);
                s2[f] = fmaf(q1, x1, s2[f]);
            }
        }
        buf ^= 1;
    }

    if (!WRITE_OUT) {
#pragma unroll
        for (int off = 32; off > 0; off >>= 1) {
            s0 += __shfl_down(s0, off);
#pragma unroll
            for (int f = 0; f < FF; ++f) {
                s1[f] += __shfl_down(s1[f], off);
                s2[f] += __shfl_down(s2[f], off);
            }
        }
        if (lane == 0) {
            // unique row per (b,k,g): plain stores, zero contention
            float* row = partials + ((size_t)(b * KK + w) * GG + g) * PSTRIDE;
#pragma unroll
            for (int f = 0; f < FF; ++f) { row[f] = s1[f]; row[FF + f] = s2[f]; }
            row[2 * FF] = s0;
        }
    }
}

// ---- reduce partials + M-step + next-iteration coefs ----
// One block per (b,k) = 40 blocks: 4 waves split the g-reduction 4-way; 40
// extra threads redundantly sum the s0 column of ALL K clusters for the pi
// normalizer (Sum_k s0_k), so no cross-block exchange is needed.
__global__ __launch_bounds__(256) void update_kernel(const float* __restrict__ partials,
                                                     float* __restrict__ ws,
                                                     float* __restrict__ om,
                                                     float* __restrict__ ov,
                                                     float* __restrict__ op,
                                                     int write_params) {
    __shared__ float shA[4][PSTRIDE];
    __shared__ float shB[8 * KK];
    const int bk   = blockIdx.x;          // b*KK + k
    const int b    = bk / KK;
    const int tid  = threadIdx.x;
    const int w4   = tid >> 6;
    const int lane = tid & 63;

    // phase A: lane l sums partial slot l over g = w4..GG step 4 (coalesced rows)
    if (lane < PSTRIDE) {
        const float* base = partials + (size_t)bk * GG * PSTRIDE + lane;
        float sv = 0.f;
        for (int gg = w4; gg < GG; gg += 4) sv += base[(size_t)gg * PSTRIDE];
        shA[w4][lane] = sv;
    }
    // phase B: total cluster size over all K clusters (for pi / A)
    if (tid < 8 * KK) {
        const int kp = tid >> 3, j = tid & 7;
        const float* cb = partials + (size_t)(b * KK + kp) * GG * PSTRIDE + 2 * FF;
        float s = 0.f;
        for (int gg = j; gg < GG; gg += 8) s += cb[(size_t)gg * PSTRIDE];
        shB[tid] = s;
    }
    __syncthreads();

    if (tid < 64) {
        float svt = 0.f;
        if (lane < PSTRIDE)
            svt = shA[0][lane] + shA[1][lane] + shA[2][lane] + shA[3][lane];

        float tb = (lane < 8 * KK) ? shB[lane] : 0.f;
#pragma unroll
        for (int off = 32; off > 0; off >>= 1) tb += __shfl_xor(tb, off);
        // tb = Sum_k s0_k on every lane

        float s0  = __shfl(svt, 2 * FF);          // this cluster's size
        float den = s0 + 1e-7f;
        float m   = svt / den;                    // meaningful on lanes 0..19 (svt = S1[f])
        float s2f = __shfl(svt, FF + (lane % FF));// S2[f] for lane f
        float var = (s2f - 2.f * m * svt + m * m * s0) / den + 1e-6f;  // lanes 0..19

        float* cm = ws + WS_CM; float* cv = ws + WS_CV; float* cp = ws + WS_CP;
        if (lane < FF) {
            cm[bk * FF + lane] = m;
            cv[bk * FF + lane] = var;
            if (write_params) { om[bk * FF + lane] = m; ov[bk * FF + lane] = var; }
        }

        float pr = (s0 / (float)NPTS) / fmaxf(tb / (float)NPTS, 1e-12f);
        if (lane == 0) {
            cp[bk] = pr;
            if (write_params) op[bk] = pr;
        }

        // coefs for next E-step, computed in-register
        float ic = 1.f / (var + 1e-6f);
        if (lane < FF) {
            (ws + WS_D)[bk * FF + lane] = ic * m;
            (ws + WS_E)[bk * FF + lane] = -0.5f * ic;
        }
        float t1 = (lane < FF) ? logf(6.283185307179586f * var) : 0.f;
        float t2 = (lane < FF) ? ic * m * m : 0.f;
#pragma unroll
        for (int off = 1; off < 64; off <<= 1) {
            t1 += __shfl_xor(t1, off);
            t2 += __shfl_xor(t2, off);
        }
        if (lane == 0)
            (ws + WS_A)[bk] = logf(pr) - 0.5f * t1 - 0.5f * t2;
    }
}

extern "C" void kernel_launch(void* const* d_in, const int* in_sizes, int n_in,
                              void* d_out, int out_size, void* d_ws, size_t ws_size,
                              hipStream_t stream) {
    const float* data     = (const float*)d_in[0];
    const float* in_means = (const float*)d_in[1];
    const float* in_var   = (const float*)d_in[2];
    const float* in_pi    = (const float*)d_in[3];
    float* ws  = (float*)d_ws;
    float* out = (float*)d_out;

    float* out_ll   = out;
    float* out_post = out + (size_t)BB * NPTS * KK;
    float* om       = out + 2 * (size_t)BB * NPTS * KK;
    float* ov       = om + BB * KK * FF;
    float* op       = ov + BB * KK * FF;

    // partial-sum buffer (1.5 MB) lives in the not-yet-needed ll output region;
    // the final E-step fully overwrites it.
    float* partials = out_ll;

    prepare_kernel<<<1, 64, 0, stream>>>(in_means, in_var, in_pi, ws);

    for (int it = 0; it < 5; ++it) {
        estep_kernel<false><<<BB * GG, 320, 0, stream>>>(data, ws, partials,
                                                         nullptr, nullptr);
        update_kernel<<<BB * KK, 256, 0, stream>>>(partials, ws, om, ov, op,
                                                   (it == 4) ? 1 : 0);
    }
    // final E-step with post-loop params: write ll/post outputs
    estep_kernel<true><<<BB * GG, 320, 0, stream>>>(data, ws, nullptr,
                                                    out_ll, out_post);
}

// Round 3
// 364.835 us; speedup vs baseline: 1.7022x; 1.1647x over previous
//
#include <hip/hip_runtime.h>
#include <math.h>

#define BB 8
#define NPTS 80000
#define KK 5
#define FF 20
#define GG 128                 // blocks per batch -> 1024 blocks = 4 blocks/CU exactly
#define TILE 128
#define NTILES (NPTS / TILE)   // 625, exact
#define PSTRIDE 48             // padded partial row: 20 s1 + 20 s2 + 1 s0 + pad

// workspace layout (float offsets) -- small params/coefs only
#define WS_CM 0          // cur means  [B,K,F] = 800
#define WS_CV 800        // cur var    = 800
#define WS_CP 1600       // cur pi     = 40
#define WS_A  1640       // A coef     = 40
#define WS_D  1680       // d coef     = 800
#define WS_E  2480       // e coef     = 800

// Raw barrier: drain LDS ops (cross-wave visibility) but leave global loads
// in flight. __syncthreads() would emit s_waitcnt vmcnt(0) and kill the
// prefetch pipeline (guide §5: barrier drain). Memory clobber pins all
// compiler-emitted ds/global ops on their side of the barrier.
#define WAIT_BAR() asm volatile("s_waitcnt lgkmcnt(0)\n\ts_barrier" ::: "memory")

// ---- compute A/d/e from (means,var,pi) ----
__device__ __forceinline__ void make_coefs(const float* __restrict__ means,
                                           const float* __restrict__ var,
                                           const float* __restrict__ pi,
                                           float* __restrict__ A, float* __restrict__ D,
                                           float* __restrict__ E, int t) {
    if (t < BB * KK) {
        float sumlog = 0.f, summ2 = 0.f;
        for (int f = 0; f < FF; ++f) {
            float v = var[t * FF + f];
            float m = means[t * FF + f];
            float ic = 1.f / (v + 1e-6f);
            sumlog += logf(6.283185307179586f * v);
            summ2  += ic * m * m;
            D[t * FF + f] = ic * m;
            E[t * FF + f] = -0.5f * ic;
        }
        A[t] = logf(pi[t]) - 0.5f * sumlog - 0.5f * summ2;
    }
}

__global__ void prepare_kernel(const float* __restrict__ means, const float* __restrict__ var,
                               const float* __restrict__ pi, float* __restrict__ ws) {
    make_coefs(means, var, pi, ws + WS_A, ws + WS_D, ws + WS_E, (int)threadIdx.x);
}

// ---- E-step: per-wave cluster, 2 points per lane, double-buffered LDS tile ----
// Pipeline per iteration t (manual barriers, loads never drained at a barrier):
//   top:   issue global loads for tile t+GG into va/vb        (stay outstanding)
//   zphase: ds_read xs[buf] -> z ; ds_write lls
//   WAIT_BAR (A): lls visible; vmcnt NOT drained
//   softmax + accumulate (re-reads xs[buf])                    (hides load latency)
//   stage:  ds_write va/vb -> xs[buf^1]  (compiler inserts the vmcnt wait here)
//   WAIT_BAR (B)
// xs[buf] is overwritten only two barriers later -> race-free.
template <bool WRITE_OUT>
__global__ __launch_bounds__(320) void estep_kernel(const float* __restrict__ data,
                                                    const float* __restrict__ ws,
                                                    float* __restrict__ partials,
                                                    float* __restrict__ out_ll,
                                                    float* __restrict__ out_post) {
    __shared__ float xs[2][FF][TILE + 1];   // transposed: x[f]=xs[buf][f][p], stride-1 reads
    __shared__ float lls[KK][TILE];

    const int b    = blockIdx.x / GG;
    const int g    = blockIdx.x % GG;
    const int tid  = threadIdx.x;
    const int w    = __builtin_amdgcn_readfirstlane(tid >> 6);   // cluster k, wave-uniform
    const int lane = tid & 63;
    const int fi   = tid * 8;                 // first staged float index in tile
    const int sp0  = fi / FF,       sf0 = fi % FF;        // 4-aligned feature block
    const int sp1  = (fi + 4) / FF, sf1 = (fi + 4) % FF;

    const float* A = ws + WS_A;
    const float* D = ws + WS_D;
    const float* E = ws + WS_E;

    const float Ak = A[b * KK + w];
    float dk[FF], ek[FF];                 // wave-uniform -> SGPRs
#pragma unroll
    for (int f = 0; f < FF; ++f) {
        dk[f] = D[(b * KK + w) * FF + f];
        ek[f] = E[(b * KK + w) * FF + f];
    }

    float s0 = 0.f, s1[FF], s2[FF];
    if (!WRITE_OUT) {
#pragma unroll
        for (int f = 0; f < FF; ++f) { s1[f] = 0.f; s2[f] = 0.f; }
    }

    const float* dbase = data + (size_t)b * NPTS * FF;

    // prologue: load + stage tile g, one full barrier (single vmcnt drain, ok)
    const float4* tpf = (const float4*)(dbase + (size_t)g * TILE * FF);
    float4 va = tpf[2 * tid];
    float4 vb = tpf[2 * tid + 1];
    xs[0][sf0][sp0]     = va.x;
    xs[0][sf0 + 1][sp0] = va.y;
    xs[0][sf0 + 2][sp0] = va.z;
    xs[0][sf0 + 3][sp0] = va.w;
    xs[0][sf1][sp1]     = vb.x;
    xs[0][sf1 + 1][sp1] = vb.y;
    xs[0][sf1 + 2][sp1] = vb.z;
    xs[0][sf1 + 3][sp1] = vb.w;
    __syncthreads();
    int buf = 0;

    for (int t = g; t < NTILES; t += GG) {
        const int tn = t + GG;
        if (tn < NTILES) {
            const float4* tp = (const float4*)(dbase + (size_t)tn * TILE * FF);
            va = tp[2 * tid];          // outstanding across barrier A
            vb = tp[2 * tid + 1];
        }

        float z0 = Ak, z1 = Ak;
#pragma unroll
        for (int f = 0; f < FF; ++f) {
            float x0 = xs[buf][f][lane];
            float x1 = xs[buf][f][lane + 64];
            z0 = fmaf(x0, fmaf(ek[f], x0, dk[f]), z0);
            z1 = fmaf(x1, fmaf(ek[f], x1, dk[f]), z1);
        }
        lls[w][lane]      = z0;
        lls[w][lane + 64] = z1;
        WAIT_BAR();                    // A: lls visible, loads still in flight

        // softmax for point p0 = lane
        float a0 = lls[0][lane], a1 = lls[1][lane], a2 = lls[2][lane],
              a3 = lls[3][lane], a4 = lls[4][lane];
        float mx0 = fmaxf(fmaxf(fmaxf(a0, a1), fmaxf(a2, a3)), a4);
        float e0 = __expf(a0 - mx0), e1 = __expf(a1 - mx0), e2 = __expf(a2 - mx0),
              e3 = __expf(a3 - mx0), e4 = __expf(a4 - mx0);
        float inv0 = 1.f / (e0 + e1 + e2 + e3 + e4);
        float ew0  = (w == 0) ? e0 : (w == 1) ? e1 : (w == 2) ? e2 : (w == 3) ? e3 : e4;
        float post0 = ew0 * inv0;

        // softmax for point p1 = lane + 64
        float b0 = lls[0][lane + 64], b1 = lls[1][lane + 64], b2 = lls[2][lane + 64],
              b3 = lls[3][lane + 64], b4 = lls[4][lane + 64];
        float mx1 = fmaxf(fmaxf(fmaxf(b0, b1), fmaxf(b2, b3)), b4);
        float f0 = __expf(b0 - mx1), f1 = __expf(b1 - mx1), f2 = __expf(b2 - mx1),
              f3 = __expf(b3 - mx1), f4 = __expf(b4 - mx1);
        float inv1 = 1.f / (f0 + f1 + f2 + f3 + f4);
        float ew1  = (w == 0) ? f0 : (w == 1) ? f1 : (w == 2) ? f2 : (w == 3) ? f3 : f4;
        float post1 = ew1 * inv1;

        if (WRITE_OUT) {
            size_t o0 = ((size_t)b * NPTS + (size_t)t * TILE + lane) * KK + w;
            out_ll[o0]   = z0;
            out_post[o0] = post0;
            size_t o1 = o0 + (size_t)64 * KK;
            out_ll[o1]   = z1;
            out_post[o1] = post1;
        } else {
            s0 += post0 + post1;
#pragma unroll
            for (int f = 0; f < FF; ++f) {
                float x0 = xs[buf][f][lane];        // re-read LDS: race-safe (dbuf)
                float x1 = xs[buf][f][lane + 64];
                float q0 = post0 * x0;
                float q1 = post1 * x1;
                s1[f] += q0 + q1;
                s2[f] = fmaf(q0, x0, s2[f]);
                s2[f] = fmaf(q1, x1, s2[f]);
            }
        }

        if (tn < NTILES) {             // uniform per block
            const int nb = buf ^ 1;
            xs[nb][sf0][sp0]     = va.x;   // vmcnt wait lands here, hidden by phase above
            xs[nb][sf0 + 1][sp0] = va.y;
            xs[nb][sf0 + 2][sp0] = va.z;
            xs[nb][sf0 + 3][sp0] = va.w;
            xs[nb][sf1][sp1]     = vb.x;
            xs[nb][sf1 + 1][sp1] = vb.y;
            xs[nb][sf1 + 2][sp1] = vb.z;
            xs[nb][sf1 + 3][sp1] = vb.w;
            WAIT_BAR();                // B: staging visible for next iteration
        }
        buf ^= 1;
    }

    if (!WRITE_OUT) {
#pragma unroll
        for (int off = 32; off > 0; off >>= 1) {
            s0 += __shfl_down(s0, off);
#pragma unroll
            for (int f = 0; f < FF; ++f) {
                s1[f] += __shfl_down(s1[f], off);
                s2[f] += __shfl_down(s2[f], off);
            }
        }
        if (lane == 0) {
            // unique row per (b,k,g): plain stores, zero contention
            float* row = partials + ((size_t)(b * KK + w) * GG + g) * PSTRIDE;
#pragma unroll
            for (int f = 0; f < FF; ++f) { row[f] = s1[f]; row[FF + f] = s2[f]; }
            row[2 * FF] = s0;
        }
    }
}

// ---- reduce partials + M-step + next-iteration coefs ----
// One block per (b,k) = 40 blocks, 512 threads: 8 waves split the g-reduction
// 8-way (16 independent loads per lane instead of 48 serial ones); 40 extra
// threads redundantly sum the s0 column of ALL K clusters for the pi
// normalizer (Sum_k s0_k), so no cross-block exchange is needed.
__global__ __launch_bounds__(512) void update_kernel(const float* __restrict__ partials,
                                                     float* __restrict__ ws,
                                                     float* __restrict__ om,
                                                     float* __restrict__ ov,
                                                     float* __restrict__ op,
                                                     int write_params) {
    __shared__ float shA[8][PSTRIDE];
    __shared__ float shB[8 * KK];
    const int bk   = blockIdx.x;          // b*KK + k
    const int b    = bk / KK;
    const int tid  = threadIdx.x;
    const int w8   = tid >> 6;
    const int lane = tid & 63;

    // phase A: lane l sums partial slot l over g = w8..GG step 8 (coalesced rows)
    if (lane < PSTRIDE) {
        const float* base = partials + (size_t)bk * GG * PSTRIDE + lane;
        float sv = 0.f;
        for (int gg = w8; gg < GG; gg += 8) sv += base[(size_t)gg * PSTRIDE];
        shA[w8][lane] = sv;
    }
    // phase B: total cluster size over all K clusters (for pi / A)
    if (tid < 8 * KK) {
        const int kp = tid >> 3, j = tid & 7;
        const float* cb = partials + (size_t)(b * KK + kp) * GG * PSTRIDE + 2 * FF;
        float s = 0.f;
        for (int gg = j; gg < GG; gg += 8) s += cb[(size_t)gg * PSTRIDE];
        shB[tid] = s;
    }
    __syncthreads();

    if (tid < 64) {
        float svt = 0.f;
        if (lane < PSTRIDE) {
            svt = (shA[0][lane] + shA[1][lane]) + (shA[2][lane] + shA[3][lane])
                + (shA[4][lane] + shA[5][lane]) + (shA[6][lane] + shA[7][lane]);
        }

        float tb = (lane < 8 * KK) ? shB[lane] : 0.f;
#pragma unroll
        for (int off = 32; off > 0; off >>= 1) tb += __shfl_xor(tb, off);
        // tb = Sum_k s0_k on every lane

        float s0  = __shfl(svt, 2 * FF);          // this cluster's size
        float den = s0 + 1e-7f;
        float m   = svt / den;                    // meaningful on lanes 0..19 (svt = S1[f])
        float s2f = __shfl(svt, FF + (lane % FF));// S2[f] for lane f
        float var = (s2f - 2.f * m * svt + m * m * s0) / den + 1e-6f;  // lanes 0..19

        float* cm = ws + WS_CM; float* cv = ws + WS_CV; float* cp = ws + WS_CP;
        if (lane < FF) {
            cm[bk * FF + lane] = m;
            cv[bk * FF + lane] = var;
            if (write_params) { om[bk * FF + lane] = m; ov[bk * FF + lane] = var; }
        }

        float pr = (s0 / (float)NPTS) / fmaxf(tb / (float)NPTS, 1e-12f);
        if (lane == 0) {
            cp[bk] = pr;
            if (write_params) op[bk] = pr;
        }

        // coefs for next E-step, computed in-register
        float ic = 1.f / (var + 1e-6f);
        if (lane < FF) {
            (ws + WS_D)[bk * FF + lane] = ic * m;
            (ws + WS_E)[bk * FF + lane] = -0.5f * ic;
        }
        float t1 = (lane < FF) ? logf(6.283185307179586f * var) : 0.f;
        float t2 = (lane < FF) ? ic * m * m : 0.f;
#pragma unroll
        for (int off = 1; off < 64; off <<= 1) {
            t1 += __shfl_xor(t1, off);
            t2 += __shfl_xor(t2, off);
        }
        if (lane == 0)
            (ws + WS_A)[bk] = logf(pr) - 0.5f * t1 - 0.5f * t2;
    }
}

extern "C" void kernel_launch(void* const* d_in, const int* in_sizes, int n_in,
                              void* d_out, int out_size, void* d_ws, size_t ws_size,
                              hipStream_t stream) {
    const float* data     = (const float*)d_in[0];
    const float* in_means = (const float*)d_in[1];
    const float* in_var   = (const float*)d_in[2];
    const float* in_pi    = (const float*)d_in[3];
    float* ws  = (float*)d_ws;
    float* out = (float*)d_out;

    float* out_ll   = out;
    float* out_post = out + (size_t)BB * NPTS * KK;
    float* om       = out + 2 * (size_t)BB * NPTS * KK;
    float* ov       = om + BB * KK * FF;
    float* op       = ov + BB * KK * FF;

    // partial-sum buffer (983 KB) lives in the not-yet-needed ll output region;
    // the final E-step fully overwrites it.
    float* partials = out_ll;

    prepare_kernel<<<1, 64, 0, stream>>>(in_means, in_var, in_pi, ws);

    for (int it = 0; it < 5; ++it) {
        estep_kernel<false><<<BB * GG, 320, 0, stream>>>(data, ws, partials,
                                                         nullptr, nullptr);
        update_kernel<<<BB * KK, 512, 0, stream>>>(partials, ws, om, ov, op,
                                                   (it == 4) ? 1 : 0);
    }
    // final E-step with post-loop params: write ll/post outputs
    estep_kernel<true><<<BB * GG, 320, 0, stream>>>(data, ws, nullptr,
                                                    out_ll, out_post);
}

// Round 4
// 327.732 us; speedup vs baseline: 1.8949x; 1.1132x over previous
//
#include <hip/hip_runtime.h>
#include <math.h>

#define BB 8
#define NPTS 80000
#define KK 5
#define FF 20
#define GG 128                 // blocks per batch -> 1024 blocks = 4 blocks/CU exactly
#define TILE 64                // one point per lane
#define NTILES (NPTS / TILE)   // 1250, exact
#define PSTRIDE 48             // padded partial row: 20 s1 + 20 s2 + 1 s0 + pad

// workspace layout (float offsets) -- small params/coefs only
#define WS_CM 0          // cur means  [B,K,F] = 800
#define WS_CV 800        // cur var    = 800
#define WS_CP 1600       // cur pi     = 40
#define WS_A  1640       // A coef     = 40
#define WS_D  1680       // d coef     = 800
#define WS_E  2480       // e coef     = 800

// Raw barrier: drain LDS ops (cross-wave lls visibility) but leave global
// loads (the prefetch touch) in flight. __syncthreads() would emit
// s_waitcnt vmcnt(0) and expose the prefetch latency AT the barrier.
#define WAIT_BAR() asm volatile("s_waitcnt lgkmcnt(0)\n\ts_barrier" ::: "memory")

// ---- compute A/d/e from (means,var,pi) ----
__device__ __forceinline__ void make_coefs(const float* __restrict__ means,
                                           const float* __restrict__ var,
                                           const float* __restrict__ pi,
                                           float* __restrict__ A, float* __restrict__ D,
                                           float* __restrict__ E, int t) {
    if (t < BB * KK) {
        float sumlog = 0.f, summ2 = 0.f;
        for (int f = 0; f < FF; ++f) {
            float v = var[t * FF + f];
            float m = means[t * FF + f];
            float ic = 1.f / (v + 1e-6f);
            sumlog += logf(6.283185307179586f * v);
            summ2  += ic * m * m;
            D[t * FF + f] = ic * m;
            E[t * FF + f] = -0.5f * ic;
        }
        A[t] = logf(pi[t]) - 0.5f * sumlog - 0.5f * summ2;
    }
}

__global__ void prepare_kernel(const float* __restrict__ means, const float* __restrict__ var,
                               const float* __restrict__ pi, float* __restrict__ ws) {
    make_coefs(means, var, pi, ws + WS_A, ws + WS_D, ws + WS_E, (int)threadIdx.x);
}

// ---- E-step: lane = point, wave = cluster; x lives in REGISTERS ----
// All 5 waves load the SAME 64-point tile from global: the per-CU L1 (32 KB,
// shared by all SIMDs) serves 4 of the 5 copies -> no LDS staging needed.
// Only LDS use: the 5-way z exchange for softmax (lls, double-buffered, ONE
// barrier per iteration; buffer pb is read in window (BAR_i, BAR_i+1) and
// next written after BAR_i+1 -> disjoint, race-free).
// DS ops per wave-iter: 6 (was 30); barriers per iter: 1 (was 2).
template <bool WRITE_OUT>
__global__ __launch_bounds__(320) void estep_kernel(const float* __restrict__ data,
                                                    const float* __restrict__ ws,
                                                    float* __restrict__ partials,
                                                    float* __restrict__ out_ll,
                                                    float* __restrict__ out_post) {
    __shared__ float lls[2][KK][TILE];   // 2.5 KB total

    const int b    = blockIdx.x / GG;
    const int g    = blockIdx.x % GG;
    const int tid  = threadIdx.x;
    const int w    = __builtin_amdgcn_readfirstlane(tid >> 6);   // cluster k, wave-uniform
    const int lane = tid & 63;

    const float* A = ws + WS_A;
    const float* D = ws + WS_D;
    const float* E = ws + WS_E;

    const float Ak = A[b * KK + w];
    float dk[FF], ek[FF];                 // wave-uniform -> SGPRs
#pragma unroll
    for (int f = 0; f < FF; ++f) {
        dk[f] = D[(b * KK + w) * FF + f];
        ek[f] = E[(b * KK + w) * FF + f];
    }

    float s0 = 0.f, s1[FF], s2[FF];
    if (!WRITE_OUT) {
#pragma unroll
        for (int f = 0; f < FF; ++f) { s1[f] = 0.f; s2[f] = 0.f; }
    }

    const float* dbase = data + (size_t)b * NPTS * FF;
    int pb = 0;

    for (int t = g; t < NTILES; t += GG) {
        // lane-owned point: 20 floats -> 5 x dwordx4, 16B-aligned (80B stride)
        const float* xp = dbase + ((size_t)t * TILE + lane) * FF;
        float4 xa = ((const float4*)xp)[0];
        float4 xb = ((const float4*)xp)[1];
        float4 xc = ((const float4*)xp)[2];
        float4 xd = ((const float4*)xp)[3];
        float4 xe = ((const float4*)xp)[4];

        // prefetch touch: one b32 per lane of the next tile warms every 80 B
        // -> all 40 cache lines of the 5 KB tile; kept alive by asm at loop
        // bottom; stays outstanding across WAIT_BAR (no vmcnt drain there).
        float pf = 0.f;
        const int tn = t + GG;
        if (tn < NTILES) pf = dbase[((size_t)tn * TILE + lane) * FF];

        float x[FF];
        x[0]=xa.x; x[1]=xa.y; x[2]=xa.z; x[3]=xa.w;
        x[4]=xb.x; x[5]=xb.y; x[6]=xb.z; x[7]=xb.w;
        x[8]=xc.x; x[9]=xc.y; x[10]=xc.z; x[11]=xc.w;
        x[12]=xd.x; x[13]=xd.y; x[14]=xd.z; x[15]=xd.w;
        x[16]=xe.x; x[17]=xe.y; x[18]=xe.z; x[19]=xe.w;

        // z = Ak + sum_f x*(ek*x + dk), two interleaved chains for ILP
        float za = 0.f, zb = 0.f;
#pragma unroll
        for (int f = 0; f < FF; f += 2) {
            za = fmaf(x[f],     fmaf(ek[f],     x[f],     dk[f]),     za);
            zb = fmaf(x[f + 1], fmaf(ek[f + 1], x[f + 1], dk[f + 1]), zb);
        }
        float z = Ak + za + zb;

        lls[pb][w][lane] = z;
        WAIT_BAR();                       // lls visible; prefetch still in flight

        float l0 = lls[pb][0][lane], l1 = lls[pb][1][lane], l2 = lls[pb][2][lane],
              l3 = lls[pb][3][lane], l4 = lls[pb][4][lane];
        float mx = fmaxf(fmaxf(fmaxf(l0, l1), fmaxf(l2, l3)), l4);
        float e0 = __expf(l0 - mx), e1 = __expf(l1 - mx), e2 = __expf(l2 - mx),
              e3 = __expf(l3 - mx), e4 = __expf(l4 - mx);
        float inv = 1.f / (e0 + e1 + e2 + e3 + e4);
        float ew  = (w == 0) ? e0 : (w == 1) ? e1 : (w == 2) ? e2 : (w == 3) ? e3 : e4;
        float post = ew * inv;

        if (WRITE_OUT) {
            size_t o = ((size_t)b * NPTS + (size_t)t * TILE + lane) * KK + w;
            out_ll[o]   = z;
            out_post[o] = post;
        } else {
            s0 += post;
#pragma unroll
            for (int f = 0; f < FF; ++f) {
                float px = post * x[f];
                s1[f] += px;
                s2[f] = fmaf(px, x[f], s2[f]);
            }
        }
        asm volatile("" :: "v"(pf));      // keep prefetch load alive (rule #17)
        pb ^= 1;
    }

    if (!WRITE_OUT) {
#pragma unroll
        for (int off = 32; off > 0; off >>= 1) {
            s0 += __shfl_down(s0, off);
#pragma unroll
            for (int f = 0; f < FF; ++f) {
                s1[f] += __shfl_down(s1[f], off);
                s2[f] += __shfl_down(s2[f], off);
            }
        }
        if (lane == 0) {
            // unique row per (b,k,g): plain stores, zero contention
            float* row = partials + ((size_t)(b * KK + w) * GG + g) * PSTRIDE;
#pragma unroll
            for (int f = 0; f < FF; ++f) { row[f] = s1[f]; row[FF + f] = s2[f]; }
            row[2 * FF] = s0;
        }
    }
}

// ---- reduce partials + M-step + next-iteration coefs ----
// One block per (b,k) = 40 blocks, 512 threads: 8 waves split the g-reduction
// 8-way; 40 extra threads redundantly sum the s0 column of ALL K clusters for
// the pi normalizer (Sum_k s0_k), so no cross-block exchange is needed.
__global__ __launch_bounds__(512) void update_kernel(const float* __restrict__ partials,
                                                     float* __restrict__ ws,
                                                     float* __restrict__ om,
                                                     float* __restrict__ ov,
                                                     float* __restrict__ op,
                                                     int write_params) {
    __shared__ float shA[8][PSTRIDE];
    __shared__ float shB[8 * KK];
    const int bk   = blockIdx.x;          // b*KK + k
    const int b    = bk / KK;
    const int tid  = threadIdx.x;
    const int w8   = tid >> 6;
    const int lane = tid & 63;

    // phase A: lane l sums partial slot l over g = w8..GG step 8 (coalesced rows)
    if (lane < PSTRIDE) {
        const float* base = partials + (size_t)bk * GG * PSTRIDE + lane;
        float sv = 0.f;
        for (int gg = w8; gg < GG; gg += 8) sv += base[(size_t)gg * PSTRIDE];
        shA[w8][lane] = sv;
    }
    // phase B: total cluster size over all K clusters (for pi / A)
    if (tid < 8 * KK) {
        const int kp = tid >> 3, j = tid & 7;
        const float* cb = partials + (size_t)(b * KK + kp) * GG * PSTRIDE + 2 * FF;
        float s = 0.f;
        for (int gg = j; gg < GG; gg += 8) s += cb[(size_t)gg * PSTRIDE];
        shB[tid] = s;
    }
    __syncthreads();

    if (tid < 64) {
        float svt = 0.f;
        if (lane < PSTRIDE) {
            svt = (shA[0][lane] + shA[1][lane]) + (shA[2][lane] + shA[3][lane])
                + (shA[4][lane] + shA[5][lane]) + (shA[6][lane] + shA[7][lane]);
        }

        float tb = (lane < 8 * KK) ? shB[lane] : 0.f;
#pragma unroll
        for (int off = 32; off > 0; off >>= 1) tb += __shfl_xor(tb, off);
        // tb = Sum_k s0_k on every lane

        float s0  = __shfl(svt, 2 * FF);          // this cluster's size
        float den = s0 + 1e-7f;
        float m   = svt / den;                    // meaningful on lanes 0..19 (svt = S1[f])
        float s2f = __shfl(svt, FF + (lane % FF));// S2[f] for lane f
        float var = (s2f - 2.f * m * svt + m * m * s0) / den + 1e-6f;  // lanes 0..19

        float* cm = ws + WS_CM; float* cv = ws + WS_CV; float* cp = ws + WS_CP;
        if (lane < FF) {
            cm[bk * FF + lane] = m;
            cv[bk * FF + lane] = var;
            if (write_params) { om[bk * FF + lane] = m; ov[bk * FF + lane] = var; }
        }

        float pr = (s0 / (float)NPTS) / fmaxf(tb / (float)NPTS, 1e-12f);
        if (lane == 0) {
            cp[bk] = pr;
            if (write_params) op[bk] = pr;
        }

        // coefs for next E-step, computed in-register
        float ic = 1.f / (var + 1e-6f);
        if (lane < FF) {
            (ws + WS_D)[bk * FF + lane] = ic * m;
            (ws + WS_E)[bk * FF + lane] = -0.5f * ic;
        }
        float t1 = (lane < FF) ? logf(6.283185307179586f * var) : 0.f;
        float t2 = (lane < FF) ? ic * m * m : 0.f;
#pragma unroll
        for (int off = 1; off < 64; off <<= 1) {
            t1 += __shfl_xor(t1, off);
            t2 += __shfl_xor(t2, off);
        }
        if (lane == 0)
            (ws + WS_A)[bk] = logf(pr) - 0.5f * t1 - 0.5f * t2;
    }
}

extern "C" void kernel_launch(void* const* d_in, const int* in_sizes, int n_in,
                              void* d_out, int out_size, void* d_ws, size_t ws_size,
                              hipStream_t stream) {
    const float* data     = (const float*)d_in[0];
    const float* in_means = (const float*)d_in[1];
    const float* in_var   = (const float*)d_in[2];
    const float* in_pi    = (const float*)d_in[3];
    float* ws  = (float*)d_ws;
    float* out = (float*)d_out;

    float* out_ll   = out;
    float* out_post = out + (size_t)BB * NPTS * KK;
    float* om       = out + 2 * (size_t)BB * NPTS * KK;
    float* ov       = om + BB * KK * FF;
    float* op       = ov + BB * KK * FF;

    // partial-sum buffer (983 KB) lives in the not-yet-needed ll output region;
    // the final E-step fully overwrites it.
    float* partials = out_ll;

    prepare_kernel<<<1, 64, 0, stream>>>(in_means, in_var, in_pi, ws);

    for (int it = 0; it < 5; ++it) {
        estep_kernel<false><<<BB * GG, 320, 0, stream>>>(data, ws, partials,
                                                         nullptr, nullptr);
        update_kernel<<<BB * KK, 512, 0, stream>>>(partials, ws, om, ov, op,
                                                   (it == 4) ? 1 : 0);
    }
    // final E-step with post-loop params: write ll/post outputs
    estep_kernel<true><<<BB * GG, 320, 0, stream>>>(data, ws, nullptr,
                                                    out_ll, out_post);
}